// Round 6
// baseline (225.954 us; speedup 1.0000x reference)
//
#include <hip/hip_runtime.h>
#include <math.h>

// Problem constants (B,C,H,W) = (16,20,256,256), fp32 in, 4 fp32 scalars out.
constexpr int Bn = 16, Cn = 20, Hn = 256, Wn = 256;
constexpr int BCn = Bn * Cn;                 // 320 slices
constexpr int HWn = Hn * Wn;                 // 65536 per slice
constexpr int SPLIT = 4;                     // blocks per slice
constexpr int NBLK = BCn * SPLIT;            // 1280 blocks = 5 per CU, uniform
constexpr int CHUNK = HWn / SPLIT;           // 16384 elems per block
constexpr int TPB = 1024;                    // 16 waves per block
constexpr int NWAVE = TPB / 64;
constexpr int V4 = CHUNK / (TPB * 4);        // 4 float4 per thread
constexpr int NSLOT = 10;
// slots: 0 mass, 1 sum(t*y), 2 sum(t*x), 3 sum(p), 4 sum(p*y), 5 sum(p*x),
//        6 sum(p*(y^2+x^2)), 7 SUM(at*om^2*ln(pt))  [negated in finalize],
//        8 (pred-t)^2, 9 |pred|

__device__ inline float wave_reduce(float v) {
    #pragma unroll
    for (int o = 32; o > 0; o >>= 1) v += __shfl_down(v, o, 64);
    return v;
}

// Round-5 post-mortem: 256-thread blocks never exceeded ~2 resident
// blocks/CU (occ 21-39%) -> stall-dominated (issue floor ~21us, measured
// 66us). 1024-thread blocks guarantee 16 waves co-resident per CU per
// block; (1024,8) caps VGPR at 64 so 2 blocks/CU fit.
__global__ __launch_bounds__(TPB, 8) void partials_kernel(
        const float* __restrict__ pred, const float* __restrict__ target,
        float* __restrict__ ws) {
    const int blk = blockIdx.x;
    const int bc = blk >> 2;                 // / SPLIT
    const int chunk = blk & (SPLIT - 1);
    const long long base = (long long)bc * HWn + (long long)chunk * CHUNK;
    const float4* __restrict__ p4 = (const float4*)(pred + base);
    const float4* __restrict__ t4 = (const float4*)(target + base);
    const int tid = threadIdx.x;

    float acc[NSLOT];
    #pragma unroll
    for (int k = 0; k < NSLOT; k++) acc[k] = 0.f;

    // Element index in slice = chunk*CHUNK + tid*4 + i*4096.
    // i*4096 is a multiple of W=256 -> x loop-invariant, y steps by 16.
    const int e_base = chunk * CHUNK + tid * 4;
    const float x0 = (float)(e_base & 255);
    const float x1 = x0 + 1.f, x2 = x0 + 2.f, x3 = x0 + 3.f;
    const float xs[4]  = {x0, x1, x2, x3};
    const float xxs[4] = {x0 * x0, x1 * x1, x2 * x2, x3 * x3};
    float y = (float)(e_base >> 8);

    float4 pc = p4[tid];
    float4 tc = t4[tid];

    #pragma unroll
    for (int i = 0; i < V4; i++) {
        float4 pn, tn;
        if (i + 1 < V4) {                    // depth-1 rotating prefetch
            pn = p4[(i + 1) * TPB + tid];
            tn = t4[(i + 1) * TPB + tid];
        }
        const float yy = y * y;
        const float pvals[4] = {pc.x, pc.y, pc.z, pc.w};
        const float tvals[4] = {tc.x, tc.y, tc.z, tc.w};
        #pragma unroll
        for (int j = 0; j < 4; j++) {
            const float v = pvals[j];
            const float t = tvals[j];
            const float x = xs[j];
            const float e = __expf(-v);                      // e^{-v}
            const float p = __builtin_amdgcn_rcpf(1.0f + e); // sigmoid
            // focal: ln(pt) = ln p - (pos ? 0 : v); 1-pt = pos ? 1-p : p
            const bool pos = (t > 0.5f);
            const float lp = __logf(p);
            const float lpt = pos ? lp : lp - v;
            const float om = pos ? 1.0f - p : p;
            const float at = pos ? 0.25f : 0.75f;
            acc[7] = fmaf(at * lpt, om * om, acc[7]);        // negate later
            // sparsity
            const float d = v - t;
            acc[8] = fmaf(d, d, acc[8]);
            acc[9] += fabsf(v);
            // concentration partials
            acc[0] += t;
            acc[1] = fmaf(t, y, acc[1]);
            acc[2] = fmaf(t, x, acc[2]);
            acc[3] += p;
            acc[4] = fmaf(p, y, acc[4]);
            acc[5] = fmaf(p, x, acc[5]);
            acc[6] = fmaf(p, yy + xxs[j], acc[6]);
        }
        y += 16.0f;
        if (i + 1 < V4) { pc = pn; tc = tn; }
    }

    __shared__ float lds[NWAVE][NSLOT];
    const int lane = tid & 63, wave = tid >> 6;
    #pragma unroll
    for (int k = 0; k < NSLOT; k++) {
        const float r = wave_reduce(acc[k]);
        if (lane == 0) lds[wave][k] = r;
    }
    __syncthreads();
    if (tid < NSLOT) {
        float s = 0.f;
        #pragma unroll
        for (int w = 0; w < NWAVE; w++) s += lds[w][tid];
        ws[blk * NSLOT + tid] = s;
    }
}

__global__ __launch_bounds__(512) void finalize_kernel(
        const float* __restrict__ ws, float* __restrict__ out) {
    const int tid = threadIdx.x;

    // Per-(b,c) concentration term (threads 0..319)
    float conc_sum = 0.f, nvalid = 0.f;
    if (tid < BCn) {
        float mass = 0, sty = 0, stx = 0, sp = 0, spy = 0, spx = 0, sprr = 0;
        for (int s = 0; s < SPLIT; s++) {
            const float* w = ws + (size_t)(tid * SPLIT + s) * NSLOT;
            mass += w[0]; sty += w[1]; stx += w[2]; sp += w[3];
            spy  += w[4]; spx += w[5]; sprr += w[6];
        }
        const bool valid = mass > 0.f;
        const float sm = valid ? mass : 1.0f;
        const float cy = sty / sm, cx = stx / sm;
        const float pdsq = sprr - 2.f * cy * spy - 2.f * cx * spx
                         + (cy * cy + cx * cx) * sp;
        conc_sum = valid ? (pdsq / (float)HWn) : 0.f;   // per-sample mean
        nvalid   = valid ? 1.f : 0.f;
    }

    // Global focal / sparsity sums over all partial blocks
    float foc = 0.f, sq = 0.f, ab = 0.f;
    for (int blk = tid; blk < NBLK; blk += 512) {
        const float* w = ws + (size_t)blk * NSLOT;
        foc += w[7]; sq += w[8]; ab += w[9];
    }

    __shared__ float lds[8][5];
    const int lane = tid & 63, wave = tid >> 6;
    float vals[5] = {conc_sum, nvalid, foc, sq, ab};
    #pragma unroll
    for (int k = 0; k < 5; k++) {
        const float r = wave_reduce(vals[k]);
        if (lane == 0) lds[wave][k] = r;
    }
    __syncthreads();

    if (tid == 0) {
        float tot[5];
        #pragma unroll
        for (int k = 0; k < 5; k++) {
            float s = 0.f;
            #pragma unroll
            for (int w = 0; w < 8; w++) s += lds[w][k];
            tot[k] = s;
        }
        const float NTOT = (float)Bn * Cn * Hn * Wn;   // 20971520
        const float focal = -tot[2] / NTOT;            // slot7 = +sum(at*om^2*ln pt)
        const float sparsity = tot[3] / NTOT + tot[4] / NTOT;
        const float concentration =
            (tot[1] > 0.f) ? (tot[0] / fmaxf(tot[1], 1.f)) : 0.f;
        const float total = 1.0f * focal + 0.8f * sparsity + 1.5f * concentration;
        out[0] = total;
        out[1] = focal;
        out[2] = sparsity;
        out[3] = concentration;
    }
}

extern "C" void kernel_launch(void* const* d_in, const int* in_sizes, int n_in,
                              void* d_out, int out_size, void* d_ws, size_t ws_size,
                              hipStream_t stream) {
    const float* pred   = (const float*)d_in[0];
    const float* target = (const float*)d_in[1];
    float* out = (float*)d_out;
    float* ws  = (float*)d_ws;   // needs NBLK*NSLOT*4 = 51.2 KB

    partials_kernel<<<NBLK, TPB, 0, stream>>>(pred, target, ws);
    finalize_kernel<<<1, 512, 0, stream>>>(ws, out);
}

// Round 7
// 189.259 us; speedup vs baseline: 1.1939x; 1.1939x over previous
//
#include <hip/hip_runtime.h>
#include <math.h>

// Problem constants (B,C,H,W) = (16,20,256,256), fp32 in, 4 fp32 scalars out.
constexpr int Bn = 16, Cn = 20, Hn = 256, Wn = 256;
constexpr int BCn = Bn * Cn;                 // 320 slices
constexpr int HWn = Hn * Wn;                 // 65536 per slice
constexpr int SPLIT = 4;                     // blocks per slice
constexpr int NBLK = BCn * SPLIT;            // 1280 blocks = 5 per CU, uniform
constexpr int CHUNK = HWn / SPLIT;           // 16384 elems per block
constexpr int TPB = 1024;                    // 16 waves per block
constexpr int NWAVE = TPB / 64;
constexpr int V4 = CHUNK / (TPB * 4);        // 4 float4 per thread
constexpr int NSLOT = 10;
// slots: 0 mass, 1 sum(t*y), 2 sum(t*x), 3 sum(p), 4 sum(p*y), 5 sum(p*x),
//        6 sum(p*(y^2+x^2)), 7 SUM(at*om^2*ln(pt))  [negated in finalize],
//        8 (pred-t)^2, 9 |pred|

__device__ inline float wave_reduce(float v) {
    #pragma unroll
    for (int o = 32; o > 0; o >>= 1) v += __shfl_down(v, o, 64);
    return v;
}

// Round-6 post-mortem: 1024-thread blocks DID fix residency (occ 21->71%)
// but (1024,8)'s 64-VGPR cap spilled 87 MB to scratch. (1024,4) = 1 block/CU
// -> 128-VGPR cap: room for the depth-1 prefetch with zero spill, and still
// 16 waves (4/SIMD) co-resident.
__global__ __launch_bounds__(TPB, 4) void partials_kernel(
        const float* __restrict__ pred, const float* __restrict__ target,
        float* __restrict__ ws) {
    const int blk = blockIdx.x;
    const int bc = blk >> 2;                 // / SPLIT
    const int chunk = blk & (SPLIT - 1);
    const long long base = (long long)bc * HWn + (long long)chunk * CHUNK;
    const float4* __restrict__ p4 = (const float4*)(pred + base);
    const float4* __restrict__ t4 = (const float4*)(target + base);
    const int tid = threadIdx.x;

    float acc[NSLOT];
    #pragma unroll
    for (int k = 0; k < NSLOT; k++) acc[k] = 0.f;

    // Element index in slice = chunk*CHUNK + tid*4 + i*4096.
    // i*4096 is a multiple of W=256 -> x loop-invariant, y steps by 16.
    const int e_base = chunk * CHUNK + tid * 4;
    const float x0 = (float)(e_base & 255);
    const float x1 = x0 + 1.f, x2 = x0 + 2.f, x3 = x0 + 3.f;
    const float xs[4]  = {x0, x1, x2, x3};
    const float xxs[4] = {x0 * x0, x1 * x1, x2 * x2, x3 * x3};
    float y = (float)(e_base >> 8);

    float4 pc = p4[tid];
    float4 tc = t4[tid];

    #pragma unroll
    for (int i = 0; i < V4; i++) {
        float4 pn, tn;
        if (i + 1 < V4) {                    // depth-1 rotating prefetch
            pn = p4[(i + 1) * TPB + tid];
            tn = t4[(i + 1) * TPB + tid];
        }
        const float yy = y * y;
        const float pvals[4] = {pc.x, pc.y, pc.z, pc.w};
        const float tvals[4] = {tc.x, tc.y, tc.z, tc.w};
        #pragma unroll
        for (int j = 0; j < 4; j++) {
            const float v = pvals[j];
            const float t = tvals[j];
            const float x = xs[j];
            const float e = __expf(-v);                      // e^{-v}
            const float p = __builtin_amdgcn_rcpf(1.0f + e); // sigmoid
            // focal: ln(pt) = ln p - (pos ? 0 : v); 1-pt = pos ? 1-p : p
            const bool pos = (t > 0.5f);
            const float lp = __logf(p);
            const float lpt = pos ? lp : lp - v;
            const float om = pos ? 1.0f - p : p;
            const float at = pos ? 0.25f : 0.75f;
            acc[7] = fmaf(at * lpt, om * om, acc[7]);        // negate later
            // sparsity
            const float d = v - t;
            acc[8] = fmaf(d, d, acc[8]);
            acc[9] += fabsf(v);
            // concentration partials
            acc[0] += t;
            acc[1] = fmaf(t, y, acc[1]);
            acc[2] = fmaf(t, x, acc[2]);
            acc[3] += p;
            acc[4] = fmaf(p, y, acc[4]);
            acc[5] = fmaf(p, x, acc[5]);
            acc[6] = fmaf(p, yy + xxs[j], acc[6]);
        }
        y += 16.0f;
        if (i + 1 < V4) { pc = pn; tc = tn; }
    }

    __shared__ float lds[NWAVE][NSLOT];
    const int lane = tid & 63, wave = tid >> 6;
    #pragma unroll
    for (int k = 0; k < NSLOT; k++) {
        const float r = wave_reduce(acc[k]);
        if (lane == 0) lds[wave][k] = r;
    }
    __syncthreads();
    if (tid < NSLOT) {
        float s = 0.f;
        #pragma unroll
        for (int w = 0; w < NWAVE; w++) s += lds[w][tid];
        ws[blk * NSLOT + tid] = s;
    }
}

__global__ __launch_bounds__(512) void finalize_kernel(
        const float* __restrict__ ws, float* __restrict__ out) {
    const int tid = threadIdx.x;

    // Per-(b,c) concentration term (threads 0..319)
    float conc_sum = 0.f, nvalid = 0.f;
    if (tid < BCn) {
        float mass = 0, sty = 0, stx = 0, sp = 0, spy = 0, spx = 0, sprr = 0;
        for (int s = 0; s < SPLIT; s++) {
            const float* w = ws + (size_t)(tid * SPLIT + s) * NSLOT;
            mass += w[0]; sty += w[1]; stx += w[2]; sp += w[3];
            spy  += w[4]; spx += w[5]; sprr += w[6];
        }
        const bool valid = mass > 0.f;
        const float sm = valid ? mass : 1.0f;
        const float cy = sty / sm, cx = stx / sm;
        const float pdsq = sprr - 2.f * cy * spy - 2.f * cx * spx
                         + (cy * cy + cx * cx) * sp;
        conc_sum = valid ? (pdsq / (float)HWn) : 0.f;   // per-sample mean
        nvalid   = valid ? 1.f : 0.f;
    }

    // Global focal / sparsity sums over all partial blocks
    float foc = 0.f, sq = 0.f, ab = 0.f;
    for (int blk = tid; blk < NBLK; blk += 512) {
        const float* w = ws + (size_t)blk * NSLOT;
        foc += w[7]; sq += w[8]; ab += w[9];
    }

    __shared__ float lds[8][5];
    const int lane = tid & 63, wave = tid >> 6;
    float vals[5] = {conc_sum, nvalid, foc, sq, ab};
    #pragma unroll
    for (int k = 0; k < 5; k++) {
        const float r = wave_reduce(vals[k]);
        if (lane == 0) lds[wave][k] = r;
    }
    __syncthreads();

    if (tid == 0) {
        float tot[5];
        #pragma unroll
        for (int k = 0; k < 5; k++) {
            float s = 0.f;
            #pragma unroll
            for (int w = 0; w < 8; w++) s += lds[w][k];
            tot[k] = s;
        }
        const float NTOT = (float)Bn * Cn * Hn * Wn;   // 20971520
        const float focal = -tot[2] / NTOT;            // slot7 = +sum(at*om^2*ln pt)
        const float sparsity = tot[3] / NTOT + tot[4] / NTOT;
        const float concentration =
            (tot[1] > 0.f) ? (tot[0] / fmaxf(tot[1], 1.f)) : 0.f;
        const float total = 1.0f * focal + 0.8f * sparsity + 1.5f * concentration;
        out[0] = total;
        out[1] = focal;
        out[2] = sparsity;
        out[3] = concentration;
    }
}

extern "C" void kernel_launch(void* const* d_in, const int* in_sizes, int n_in,
                              void* d_out, int out_size, void* d_ws, size_t ws_size,
                              hipStream_t stream) {
    const float* pred   = (const float*)d_in[0];
    const float* target = (const float*)d_in[1];
    float* out = (float*)d_out;
    float* ws  = (float*)d_ws;   // needs NBLK*NSLOT*4 = 51.2 KB

    partials_kernel<<<NBLK, TPB, 0, stream>>>(pred, target, ws);
    finalize_kernel<<<1, 512, 0, stream>>>(ws, out);
}